// Round 20
// baseline (341.844 us; speedup 1.0000x reference)
//
#include <hip/hip_runtime.h>
#include <hip/hip_bf16.h>

typedef __attribute__((ext_vector_type(8))) short short8;
typedef __attribute__((ext_vector_type(4))) float f32x4;

#define HEADS 16
#define DH    64
#define LSEQ  512
#define CD    1024
#define MROWS 8192            /* B*T*L */

static __device__ __forceinline__ unsigned short f2bf(float f) {
    union { float f; unsigned int u; } v; v.f = f;
    unsigned int u = v.u;
    u += 0x7fffu + ((u >> 16) & 1u);   // round-to-nearest-even
    return (unsigned short)(u >> 16);
}

// pack 4 floats -> 4 fp8 e4m3 bytes (OCP, HW convert)
static __device__ __forceinline__ unsigned int pk4_fp8(float a, float b, float c, float d) {
    int v = __builtin_amdgcn_cvt_pk_fp8_f32(a, b, 0, false);   // bytes 0,1
    v = __builtin_amdgcn_cvt_pk_fp8_f32(c, d, v, true);        // bytes 2,3
    return (unsigned int)v;
}
static __device__ __forceinline__ unsigned char f2fp8(float a) {
    return (unsigned char)(__builtin_amdgcn_cvt_pk_fp8_f32(a, a, 0, false) & 0xff);
}

static __device__ __forceinline__ void gload16(const void* g, char* lds) {
    __builtin_amdgcn_global_load_lds(
        (const __attribute__((address_space(1))) void*)g,
        (__attribute__((address_space(3))) void*)lds, 16, 0, 0);
}

// ---------------- f32 -> fp8 e4m3 bulk convert (8 elems/thread) -------------
__global__ __launch_bounds__(256)
void cvt_fp8_kernel(const float* __restrict__ s, unsigned char* __restrict__ d, int n8) {
    for (int i = blockIdx.x * blockDim.x + threadIdx.x; i < n8; i += gridDim.x * blockDim.x) {
        const float4 v0 = ((const float4*)s)[2 * i];
        const float4 v1 = ((const float4*)s)[2 * i + 1];
        uint2 p;
        p.x = pk4_fp8(v0.x, v0.y, v0.z, v0.w);
        p.y = pk4_fp8(v1.x, v1.y, v1.z, v1.w);
        ((uint2*)d)[i] = p;
    }
}

// ---------------- f32 [N][CD] -> fp8 fragment-major convert ----------------
// Slot b = nt*32 + kt (nt = n/16, kt = k/32). Lane l of slot b holds 8 fp8:
// n = nt*16 + (l&15), k = kt*32 + (l>>4)*8, at byte b*512 + l*8.
__global__ __launch_bounds__(256)
void cvt_frag8_kernel(const float* __restrict__ s, unsigned char* __restrict__ d, int nthr) {
    for (int i = blockIdx.x * blockDim.x + threadIdx.x; i < nthr; i += gridDim.x * blockDim.x) {
        const int b  = i >> 6, l = i & 63;
        const int nt = b >> 5, kt = b & 31;
        const int n  = nt * 16 + (l & 15);
        const int k  = kt * 32 + (l >> 4) * 8;
        const float4 v0 = *(const float4*)(s + (size_t)n * CD + k);
        const float4 v1 = *(const float4*)(s + (size_t)n * CD + k + 4);
        uint2 p;
        p.x = pk4_fp8(v0.x, v0.y, v0.z, v0.w);
        p.y = pk4_fp8(v1.x, v1.y, v1.z, v1.w);
        *(uint2*)(d + (size_t)b * 512 + l * 8) = p;
    }
}

// ===== Kernel 1: fused QKV projection — A-persistent, K-HALF staging.
// r20 change: A panel staged in two 32KB K-halves (one mid-loop restage with
// 2 barriers) -> LDS 37KB -> 3 blocks/CU co-resident -> grid 768 fits in ONE
// dispatch wave (zero tail) at 24 waves/CU (3x r18's TLP). Barrier-free MFMA
// loop otherwise; B direct-from-L2 frag-major in-place loads (r18); coalesced
// Q/K/V stores (r17).
__global__ __launch_bounds__(512, 6)
void proj_qkv_kernel(const unsigned char* __restrict__ x8,
                     const unsigned char* __restrict__ wqkvf,   // frag-major fp8
                     const float* __restrict__ bq, const float* __restrict__ bkv,
                     unsigned short* __restrict__ Qb, unsigned short* __restrict__ Kb,
                     unsigned short* __restrict__ Vtb)
{
    __shared__ __attribute__((aligned(16))) char Asm[32 * 1024];
    __shared__ __attribute__((aligned(16))) unsigned short Vb[8][16 * 20];  // bounce

    // grid = 768: im = bid&127 (64-row m-tile), sp = bid>>7 (512-col span).
    const int im = blockIdx.x & 127;
    const int sp = blockIdx.x >> 7;       // 0..5
    const int i0 = im * 64;

    const int tid  = threadIdx.x;
    const int w    = tid >> 6;            // 0..7 = n-quarter within the span
    const int lane = tid & 63;
    const int colw = lane & 15;
    const int grp  = lane >> 4;

    // ---- A staging constants (32KB half: 64 rows x 512B, XOR chunk swizzle) --
    // thread covers 16B: row = c*16 + (tid>>5), phys chunk = tid&31 holding
    // logical chunk (tid&31)^(row&7); row&7 = (tid>>5)&7 (c*16 ≡ 0 mod 8).
    const int r8  = (tid >> 5) & 7;
    const int lch = (tid & 31) ^ r8;
    const int arow = tid >> 5;                  // 0..15 (+c*16)
    const unsigned char* const Ag = x8 + (size_t)(i0 + arow) * CD + lch * 16;

    // stage K-half kh (4 gloads/thread)
    #define STAGE_A(KH) do {                                                  \
        _Pragma("unroll")                                                     \
        for (int c = 0; c < 4; ++c)                                           \
            gload16(Ag + (size_t)(c * 16) * CD + (KH) * 512,                  \
                    Asm + c * 8192 + tid * 16);                               \
    } while (0)

    STAGE_A(0);
    asm volatile("s_waitcnt vmcnt(0)" ::: "memory");
    __syncthreads();

    // A-frag ds_read offsets (row stride 512B within the half)
    const int khi = grp >> 1, klo = grp & 1;
    int aoff[4][4];
    #pragma unroll
    for (int mf = 0; mf < 4; ++mf)
        #pragma unroll
        for (int ks = 0; ks < 4; ++ks) {
            const int mrow = mf * 16 + colw;
            aoff[mf][ks] = mrow * 512 + (((ks * 2 + khi) ^ (mrow & 7)) << 4) + klo * 8;
        }

    // B per-lane fragment base: nt = sp*32 + w*4 (+nf)
    const unsigned char* const Bl =
        wqkvf + ((size_t)(sp * 32 + w * 4)) * 32 * 512 + lane * 8;

    f32x4 acc[4][4] = {};

    #pragma unroll
    for (int kh = 0; kh < 2; ++kh) {
        if (kh == 1) {
            __syncthreads();                       // all reads of half-0 done
            STAGE_A(1);
            asm volatile("s_waitcnt vmcnt(0)" ::: "memory");
            __syncthreads();
        }
        #pragma unroll
        for (int tl = 0; tl < 4; ++tl) {
            const int t = kh * 4 + tl;             // global K-step for B
            #pragma unroll
            for (int ks = 0; ks < 4; ++ks) {
                long long af[4], bf[4];
                #pragma unroll
                for (int mf = 0; mf < 4; ++mf)
                    af[mf] = *(const long long*)(Asm + aoff[mf][ks] + tl * 128);
                #pragma unroll
                for (int nf = 0; nf < 4; ++nf)
                    bf[nf] = *(const long long*)(Bl + nf * 16384 + (t * 4 + ks) * 512);
                __builtin_amdgcn_s_setprio(1);
                #pragma unroll
                for (int mf = 0; mf < 4; ++mf)
                    #pragma unroll
                    for (int nf = 0; nf < 4; ++nf)
                        acc[mf][nf] = __builtin_amdgcn_mfma_f32_16x16x32_fp8_fp8(
                            af[mf], bf[nf], acc[mf][nf], 0, 0, 0);
                __builtin_amdgcn_s_setprio(0);
            }
        }
    }
    #undef STAGE_A

    // ---- epilogue: bias + l2norm over 64-col head; coalesced stores ----
    const int jbase = sp * 512 + w * 64;          // head-aligned, wave-uniform
    const float* bp = (jbase < CD) ? (bq + jbase) : (bkv + (jbase - CD));
    #pragma unroll
    for (int nf = 0; nf < 4; ++nf) {
        const float bv = bp[nf * 16 + colw];
        #pragma unroll
        for (int mf = 0; mf < 4; ++mf)
            #pragma unroll
            for (int r = 0; r < 4; ++r) acc[mf][nf][r] += bv;
    }
    const float qscale = (jbase < CD) ? 0.125f : 1.0f;
    unsigned short* dst; int jloc;
    if (jbase < CD)            { dst = Qb;  jloc = jbase; }
    else if (jbase < 2 * CD)   { dst = Kb;  jloc = jbase - CD; }
    else                       { dst = Vtb; jloc = jbase - 2 * CD; }
    const int h = jloc >> 6;

    if (jbase < 2 * CD) {
        // ---- Q/K: coalesced-in-d store ----
        #pragma unroll
        for (int mf = 0; mf < 4; ++mf) {
            #pragma unroll
            for (int r = 0; r < 4; ++r) {
                float t = 0.f;
                #pragma unroll
                for (int nf = 0; nf < 4; ++nf) t += acc[mf][nf][r] * acc[mf][nf][r];
                t += __shfl_xor(t, 1);
                t += __shfl_xor(t, 2);
                t += __shfl_xor(t, 4);
                t += __shfl_xor(t, 8);
                const float inv = qscale / fmaxf(sqrtf(t), 1e-12f);
                const int i  = i0 + mf * 16 + grp * 4 + r;
                const int bt = i >> 9, li = i & 511;
                #pragma unroll
                for (int nf = 0; nf < 4; ++nf) {
                    const int d = nf * 16 + colw;
                    dst[(((size_t)(bt * HEADS + h)) * LSEQ + li) * DH + d] =
                        f2bf(acc[mf][nf][r] * inv);
                }
            }
        }
    } else {
        // ---- V: per-wave LDS bounce transpose -> coalesced-in-l store ----
        unsigned short* buf = &Vb[w][0];
        const int bt = i0 >> 9, lt = (i0 & 511) >> 6;   // one 64-token tile
        unsigned short* vdst = dst + (((size_t)(bt * HEADS + h)) * 8 + lt) * 4096;
        #pragma unroll
        for (int mf = 0; mf < 4; ++mf) {
            float inv[4];
            #pragma unroll
            for (int r = 0; r < 4; ++r) {
                float t = 0.f;
                #pragma unroll
                for (int nf = 0; nf < 4; ++nf) t += acc[mf][nf][r] * acc[mf][nf][r];
                t += __shfl_xor(t, 1);
                t += __shfl_xor(t, 2);
                t += __shfl_xor(t, 4);
                t += __shfl_xor(t, 8);
                inv[r] = 1.0f / fmaxf(sqrtf(t), 1e-12f);
            }
            const int lo = mf * 16;                     // token offset in tile
            #pragma unroll
            for (int nf = 0; nf < 4; ++nf) {
                #pragma unroll
                for (int r = 0; r < 4; ++r)
                    buf[(grp * 4 + r) * 20 + colw] = f2bf(acc[mf][nf][r] * inv[r]);
                unsigned short tv[4];
                #pragma unroll
                for (int r2 = 0; r2 < 4; ++r2)
                    tv[r2] = buf[colw * 20 + grp * 4 + r2];
                #pragma unroll
                for (int r2 = 0; r2 < 4; ++r2) {
                    const int d = nf * 16 + grp * 4 + r2;
                    vdst[d * 64 + lo + colw] = tv[r2];   // lanes contiguous in l
                }
            }
        }
    }
}

// ========== 2-phase dbuf GEMM core, FP8 inputs, BK=128 (proj_out) ==========
static __device__ __forceinline__ void gemm128_fp8_core(
    const unsigned char* __restrict__ Ap,   // [M][1024] fp8 row-major
    const unsigned char* __restrict__ Bp,   // [N][1024] fp8 row-major
    int i0, int n0, char* lds, f32x4 acc[4][4])
{
    const int tid  = threadIdx.x;
    const int wv   = tid >> 6;        // 0..3
    const int lane = tid & 63;
    const int colw = lane & 15;
    const int grp  = lane >> 4;
    const int wr   = wv >> 1;
    const int wc   = wv & 1;

    const int srow0 = lane >> 3;
    const int sclog = (lane & 7) ^ (srow0 & 7);
    const int adst  = wv * 32 * 128;
    const int bdst  = 16384 + wv * 32 * 128;

    int aoff[4][4], boff[4][4];
    #pragma unroll
    for (int ks = 0; ks < 4; ++ks) {
        #pragma unroll
        for (int f = 0; f < 4; ++f) {
            const int ra = wr * 64 + f * 16 + colw;
            const int rb = wc * 64 + f * 16 + colw;
            const int ch = ks * 2 + (grp >> 1);
            aoff[ks][f] = ra * 128 + ((ch ^ (ra & 7)) << 4) + (grp & 1) * 8;
            boff[ks][f] = 16384 + rb * 128 + ((ch ^ (rb & 7)) << 4) + (grp & 1) * 8;
        }
    }

    const int NT = CD / 128;   // 8 K-tiles

    #pragma unroll
    for (int c = 0; c < 4; ++c) {
        const int row = wv * 32 + c * 8 + srow0;
        gload16(Ap + (size_t)(i0 + row) * CD + sclog * 16, lds + adst + c * 1024);
        gload16(Bp + (size_t)(n0 + row) * CD + sclog * 16, lds + bdst + c * 1024);
    }
    asm volatile("s_waitcnt vmcnt(0)" ::: "memory");
    __builtin_amdgcn_s_barrier();

    for (int t = 0; t < NT; ++t) {
        char* const cb = lds + (t & 1) * 32768;
        char* const nb = lds + ((t & 1) ^ 1) * 32768;

        if (t + 1 < NT) {
            const int kt = (t + 1) * 128;
            #pragma unroll
            for (int c = 0; c < 4; ++c) {
                const int row = wv * 32 + c * 8 + srow0;
                gload16(Ap + (size_t)(i0 + row) * CD + kt + sclog * 16, nb + adst + c * 1024);
                gload16(Bp + (size_t)(n0 + row) * CD + kt + sclog * 16, nb + bdst + c * 1024);
            }
        }
        long long af[4][4], bf[4][4];
        #pragma unroll
        for (int ks = 0; ks < 4; ++ks) {
            #pragma unroll
            for (int f = 0; f < 4; ++f) {
                af[ks][f] = *(const long long*)(cb + aoff[ks][f]);
                bf[ks][f] = *(const long long*)(cb + boff[ks][f]);
            }
        }
        __builtin_amdgcn_s_setprio(1);
        #pragma unroll
        for (int ks = 0; ks < 4; ++ks)
            #pragma unroll
            for (int mf = 0; mf < 4; ++mf)
                #pragma unroll
                for (int nf = 0; nf < 4; ++nf)
                    acc[mf][nf] = __builtin_amdgcn_mfma_f32_16x16x32_fp8_fp8(
                        af[ks][mf], bf[ks][nf], acc[mf][nf], 0, 0, 0);
        __builtin_amdgcn_s_setprio(0);

        asm volatile("s_waitcnt vmcnt(0)" ::: "memory");
        __builtin_amdgcn_s_barrier();
    }
}

// ---------------- Kernel 2: flash attention per (b,t,h) ----------
// Bounded-score softmax (|s|<=0.125): exp(s) directly, no max tracking.
// O written as fp8 e4m3 (feeds the fp8 out-projection directly).
__global__ __launch_bounds__(512)
void attn_kernel(const unsigned short* __restrict__ Qb,
                 const unsigned short* __restrict__ Kb,
                 const unsigned short* __restrict__ Vtb,   // tiled [bth][8][64][64]
                 unsigned char* __restrict__ Ob)
{
    __shared__ __attribute__((aligned(16))) unsigned short Ksm[64 * 64];
    __shared__ __attribute__((aligned(16))) unsigned short Vsm[64 * 64];
    __shared__ __attribute__((aligned(16))) unsigned short Psm[8][16 * 72];

    const int tid  = threadIdx.x;
    const int w    = tid >> 6;        // 0..7
    const int lane = tid & 63;
    const int colw = lane & 15;
    const int grp  = lane >> 4;

    const int bth = blockIdx.x & 255;     // head id (same XCD for all its q-tiles)
    const int qt  = blockIdx.x >> 8;      // 0..3
    const int q0  = qt * 128 + w * 16;    // wave's first q row

    const unsigned short* Qh = Qb  + (size_t)bth * LSEQ * DH;
    const unsigned short* Kh = Kb  + (size_t)bth * LSEQ * DH;
    const unsigned short* Vh = Vtb + (size_t)bth * LSEQ * DH;  // tiled

    short8 aq[2];
    #pragma unroll
    for (int ks = 0; ks < 2; ++ks)
        aq[ks] = *(const short8*)&Qh[(size_t)(q0 + colw) * DH + ks * 32 + grp * 8];

    const int srow   = w * 8 + (lane >> 3);          // 0..63
    const int schunk = (lane & 7) ^ (srow & 7);      // swizzled 16B chunk
    const int goff   = srow * DH + schunk * 8;       // element offset in 8KB tile
    char* const kdst = (char*)Ksm + w * 1024;
    char* const vdst = (char*)Vsm + w * 1024;

    float plsum[4] = {0.f, 0.f, 0.f, 0.f};
    f32x4 oacc[4] = {};

    for (int t = 0; t < 8; ++t) {
        gload16(Kh + t * 4096 + goff, kdst);
        gload16(Vh + t * 4096 + goff, vdst);
        __syncthreads();                 // drains vmcnt -> tiles ready

        f32x4 s[4] = {};
        #pragma unroll
        for (int ks = 0; ks < 2; ++ks) {
            #pragma unroll
            for (int nf = 0; nf < 4; ++nf) {
                const int rowb = nf * 16 + colw;
                const short8 bk = *(const short8*)((char*)Ksm + rowb * 128 +
                                       ((((ks * 4 + grp) ^ (rowb & 7))) << 4));
                s[nf] = __builtin_amdgcn_mfma_f32_16x16x32_bf16(aq[ks], bk, s[nf], 0, 0, 0);
            }
        }
        #pragma unroll
        for (int nf = 0; nf < 4; ++nf) {
            #pragma unroll
            for (int r = 0; r < 4; ++r) {
                const float p = __expf(s[nf][r]);
                plsum[r] += p;
                Psm[w][(grp * 4 + r) * 72 + nf * 16 + colw] = f2bf(p);
            }
        }
        #pragma unroll
        for (int ks2 = 0; ks2 < 2; ++ks2) {
            const short8 ap = *(const short8*)&Psm[w][colw * 72 + ks2 * 32 + grp * 8];
            #pragma unroll
            for (int nf = 0; nf < 4; ++nf) {
                const int rowv = nf * 16 + colw;
                const short8 bv = *(const short8*)((char*)Vsm + rowv * 128 +
                                       ((((ks2 * 4 + grp) ^ (rowv & 7))) << 4));
                oacc[nf] = __builtin_amdgcn_mfma_f32_16x16x32_bf16(ap, bv, oacc[nf], 0, 0, 0);
            }
        }
        __syncthreads();                 // protect LDS tiles before restage
    }

    float oinv[4];
    #pragma unroll
    for (int r = 0; r < 4; ++r) {
        float t = plsum[r];
        t += __shfl_xor(t, 1);
        t += __shfl_xor(t, 2);
        t += __shfl_xor(t, 4);
        t += __shfl_xor(t, 8);
        oinv[r] = 1.0f / t;
    }

    const int bt = bth >> 4, h = bth & 15;
    #pragma unroll
    for (int nf = 0; nf < 4; ++nf) {
        #pragma unroll
        for (int r = 0; r < 4; ++r) {
            const int i = bt * LSEQ + q0 + grp * 4 + r;
            const int c = h * 64 + nf * 16 + colw;
            Ob[(size_t)i * CD + c] = f2fp8(oacc[nf][r] * oinv[r]);
        }
    }
}

// ---------------- Kernel 3: output projection + bias + residual ----------
__global__ __launch_bounds__(256, 2)
void proj_out_kernel(const unsigned char* __restrict__ O8,
                     const unsigned char* __restrict__ wm8,
                     const float* __restrict__ bm,
                     const float* __restrict__ x, float* __restrict__ out)
{
    __shared__ __attribute__((aligned(16))) char lds[64 * 1024];

    // grid = 512. XCD partition: 16m x 4n rectangle per XCD.
    const int xcd = blockIdx.x & 7, wgl = blockIdx.x >> 3;   // wgl 0..63
    const int im  = (xcd & 3) * 16 + (wgl >> 2);
    const int in  = (xcd >> 2) * 4 + (wgl & 3);
    const int i0 = im * 128, j0 = in * 128;

    const int tid  = threadIdx.x;
    const int wv   = tid >> 6;
    const int lane = tid & 63;
    const int colw = lane & 15;
    const int grp  = lane >> 4;
    const int wr   = wv >> 1, wc = wv & 1;

    f32x4 acc[4][4] = {};
    gemm128_fp8_core(O8, wm8, i0, j0, lds, acc);

    #pragma unroll
    for (int nf = 0; nf < 4; ++nf) {
        const int j = j0 + wc * 64 + nf * 16 + colw;
        const float bv = bm[j];
        #pragma unroll
        for (int mf = 0; mf < 4; ++mf) {
            #pragma unroll
            for (int r = 0; r < 4; ++r) {
                const int i = i0 + wr * 64 + mf * 16 + grp * 4 + r;
                out[(size_t)i * CD + j] = acc[mf][nf][r] + bv + x[(size_t)i * CD + j];
            }
        }
    }
}

extern "C" void kernel_launch(void* const* d_in, const int* in_sizes, int n_in,
                              void* d_out, int out_size, void* d_ws, size_t ws_size,
                              hipStream_t stream) {
    const float* x   = (const float*)d_in[0];
    const float* wq  = (const float*)d_in[1];
    const float* bq  = (const float*)d_in[2];
    const float* wkv = (const float*)d_in[3];
    const float* bkv = (const float*)d_in[4];
    const float* wm  = (const float*)d_in[5];
    const float* bm  = (const float*)d_in[6];
    float* out = (float*)d_out;

    // ws layout (64 MB, timeline-aliased, byte offsets):
    //  [0,16M):  x8 fp8 (cvt->proj_qkv), then O8 fp8 (attn->proj_out)
    //  [16M,32M): Qb bf16 (proj_qkv->attn), then wm8 fp8 (cvt-after-attn->proj_out)
    //  [32M,48M): Kb bf16   [48M,64M): Vtb bf16
    // wqkvf (frag-major fp8, 3MB) lives in d_out (dead before proj_out writes it).
    char* base = (char*)d_ws;
    unsigned char*  x8    = (unsigned char*)base;
    unsigned char*  O8    = (unsigned char*)base;    // alias (x8 dead after proj_qkv)
    unsigned short* Qb    = (unsigned short*)(base + 16 * 1024 * 1024);
    unsigned char*  wm8   = (unsigned char*)(base + 16 * 1024 * 1024);  // alias after attn
    unsigned short* Kb    = (unsigned short*)(base + 32 * 1024 * 1024);
    unsigned short* Vtb   = (unsigned short*)(base + 48 * 1024 * 1024);
    unsigned char*  wqkvf = (unsigned char*)d_out;

    cvt_fp8_kernel<<<2048, 256, 0, stream>>>(x, x8, (MROWS * CD) / 8);
    // wq -> frag slots [0, 2048); wkv -> frag slots [2048, 6144)  (slot = 512B)
    cvt_frag8_kernel<<<512,  256, 0, stream>>>(wq,  wqkvf,               2048 * 64);
    cvt_frag8_kernel<<<1024, 256, 0, stream>>>(wkv, wqkvf + 2048 * 512,  4096 * 64);
    proj_qkv_kernel<<<768, 512, 0, stream>>>(x8, wqkvf, bq, bkv, Qb, Kb, Vtb);
    attn_kernel<<<1024, 512, 0, stream>>>(Qb, Kb, Vtb, O8);
    cvt_fp8_kernel<<<512, 256, 0, stream>>>(wm, wm8, (CD * CD) / 8);
    proj_out_kernel<<<512, 256, 0, stream>>>(O8, wm8, bm, x, out);
}

// Round 21
// 112.342 us; speedup vs baseline: 3.0429x; 3.0429x over previous
//
#include <hip/hip_runtime.h>
#include <hip/hip_bf16.h>

typedef __attribute__((ext_vector_type(8))) short short8;
typedef __attribute__((ext_vector_type(4))) float f32x4;

#define HEADS 16
#define DH    64
#define LSEQ  512
#define CD    1024
#define MROWS 8192            /* B*T*L */

static __device__ __forceinline__ unsigned short f2bf(float f) {
    union { float f; unsigned int u; } v; v.f = f;
    unsigned int u = v.u;
    u += 0x7fffu + ((u >> 16) & 1u);   // round-to-nearest-even
    return (unsigned short)(u >> 16);
}

// pack 4 floats -> 4 fp8 e4m3 bytes (OCP, HW convert)
static __device__ __forceinline__ unsigned int pk4_fp8(float a, float b, float c, float d) {
    int v = __builtin_amdgcn_cvt_pk_fp8_f32(a, b, 0, false);   // bytes 0,1
    v = __builtin_amdgcn_cvt_pk_fp8_f32(c, d, v, true);        // bytes 2,3
    return (unsigned int)v;
}
static __device__ __forceinline__ unsigned char f2fp8(float a) {
    return (unsigned char)(__builtin_amdgcn_cvt_pk_fp8_f32(a, a, 0, false) & 0xff);
}

static __device__ __forceinline__ void gload16(const void* g, char* lds) {
    __builtin_amdgcn_global_load_lds(
        (const __attribute__((address_space(1))) void*)g,
        (__attribute__((address_space(3))) void*)lds, 16, 0, 0);
}

// ---------------- f32 -> fp8 e4m3 bulk convert (8 elems/thread) -------------
__global__ __launch_bounds__(256)
void cvt_fp8_kernel(const float* __restrict__ s, unsigned char* __restrict__ d, int n8) {
    for (int i = blockIdx.x * blockDim.x + threadIdx.x; i < n8; i += gridDim.x * blockDim.x) {
        const float4 v0 = ((const float4*)s)[2 * i];
        const float4 v1 = ((const float4*)s)[2 * i + 1];
        uint2 p;
        p.x = pk4_fp8(v0.x, v0.y, v0.z, v0.w);
        p.y = pk4_fp8(v1.x, v1.y, v1.z, v1.w);
        ((uint2*)d)[i] = p;
    }
}

// ---------------- f32 [N][CD] -> fp8 fragment-major convert ----------------
// Slot b = nt*32 + kt (nt = n/16, kt = k/32). Lane l of slot b holds 8 fp8:
// n = nt*16 + (l&15), k = kt*32 + (l>>4)*8, at byte b*512 + l*8.
__global__ __launch_bounds__(256)
void cvt_frag8_kernel(const float* __restrict__ s, unsigned char* __restrict__ d, int nthr) {
    for (int i = blockIdx.x * blockDim.x + threadIdx.x; i < nthr; i += gridDim.x * blockDim.x) {
        const int b  = i >> 6, l = i & 63;
        const int nt = b >> 5, kt = b & 31;
        const int n  = nt * 16 + (l & 15);
        const int k  = kt * 32 + (l >> 4) * 8;
        const float4 v0 = *(const float4*)(s + (size_t)n * CD + k);
        const float4 v1 = *(const float4*)(s + (size_t)n * CD + k + 4);
        uint2 p;
        p.x = pk4_fp8(v0.x, v0.y, v0.z, v0.w);
        p.y = pk4_fp8(v1.x, v1.y, v1.z, v1.w);
        *(uint2*)(d + (size_t)b * 512 + l * 8) = p;
    }
}

// ===== Kernel 1: fused QKV projection — A-persistent, K-HALF staging (37KB).
// r21 change: launch_bounds back to (512,2). r20's (512,6) capped the UNIFIED
// VGPR+AGPR budget at ~80 while acc alone needs 64 AGPR -> accumulator spill
// to scratch (735MB writes, 280us). With the allocator unconstrained (~64
// total like r19), the HARDWARE fits 3-4 blocks/CU by LDS (37KB) and VGPR,
// giving the extra TLP r20 aimed for without spills.
__global__ __launch_bounds__(512, 2)
void proj_qkv_kernel(const unsigned char* __restrict__ x8,
                     const unsigned char* __restrict__ wqkvf,   // frag-major fp8
                     const float* __restrict__ bq, const float* __restrict__ bkv,
                     unsigned short* __restrict__ Qb, unsigned short* __restrict__ Kb,
                     unsigned short* __restrict__ Vtb)
{
    __shared__ __attribute__((aligned(16))) char Asm[32 * 1024];
    __shared__ __attribute__((aligned(16))) unsigned short Vb[8][16 * 20];  // bounce

    // grid = 768: im = bid&127 (64-row m-tile), sp = bid>>7 (512-col span).
    const int im = blockIdx.x & 127;
    const int sp = blockIdx.x >> 7;       // 0..5
    const int i0 = im * 64;

    const int tid  = threadIdx.x;
    const int w    = tid >> 6;            // 0..7 = n-quarter within the span
    const int lane = tid & 63;
    const int colw = lane & 15;
    const int grp  = lane >> 4;

    // ---- A staging constants (32KB half: 64 rows x 512B, XOR chunk swizzle) --
    const int r8  = (tid >> 5) & 7;
    const int lch = (tid & 31) ^ r8;
    const int arow = tid >> 5;                  // 0..15 (+c*16)
    const unsigned char* const Ag = x8 + (size_t)(i0 + arow) * CD + lch * 16;

    #define STAGE_A(KH) do {                                                  \
        _Pragma("unroll")                                                     \
        for (int c = 0; c < 4; ++c)                                           \
            gload16(Ag + (size_t)(c * 16) * CD + (KH) * 512,                  \
                    Asm + c * 8192 + tid * 16);                               \
    } while (0)

    STAGE_A(0);
    asm volatile("s_waitcnt vmcnt(0)" ::: "memory");
    __syncthreads();

    // A-frag ds_read offsets (row stride 512B within the half)
    const int khi = grp >> 1, klo = grp & 1;
    int aoff[4][4];
    #pragma unroll
    for (int mf = 0; mf < 4; ++mf)
        #pragma unroll
        for (int ks = 0; ks < 4; ++ks) {
            const int mrow = mf * 16 + colw;
            aoff[mf][ks] = mrow * 512 + (((ks * 2 + khi) ^ (mrow & 7)) << 4) + klo * 8;
        }

    // B per-lane fragment base: nt = sp*32 + w*4 (+nf)
    const unsigned char* const Bl =
        wqkvf + ((size_t)(sp * 32 + w * 4)) * 32 * 512 + lane * 8;

    f32x4 acc[4][4] = {};

    #pragma unroll
    for (int kh = 0; kh < 2; ++kh) {
        if (kh == 1) {
            __syncthreads();                       // all reads of half-0 done
            STAGE_A(1);
            asm volatile("s_waitcnt vmcnt(0)" ::: "memory");
            __syncthreads();
        }
        #pragma unroll
        for (int tl = 0; tl < 4; ++tl) {
            const int t = kh * 4 + tl;             // global K-step for B
            #pragma unroll
            for (int ks = 0; ks < 4; ++ks) {
                long long af[4], bf[4];
                #pragma unroll
                for (int mf = 0; mf < 4; ++mf)
                    af[mf] = *(const long long*)(Asm + aoff[mf][ks] + tl * 128);
                #pragma unroll
                for (int nf = 0; nf < 4; ++nf)
                    bf[nf] = *(const long long*)(Bl + nf * 16384 + (t * 4 + ks) * 512);
                __builtin_amdgcn_s_setprio(1);
                #pragma unroll
                for (int mf = 0; mf < 4; ++mf)
                    #pragma unroll
                    for (int nf = 0; nf < 4; ++nf)
                        acc[mf][nf] = __builtin_amdgcn_mfma_f32_16x16x32_fp8_fp8(
                            af[mf], bf[nf], acc[mf][nf], 0, 0, 0);
                __builtin_amdgcn_s_setprio(0);
            }
        }
    }
    #undef STAGE_A

    // ---- epilogue: bias + l2norm over 64-col head; coalesced stores ----
    const int jbase = sp * 512 + w * 64;          // head-aligned, wave-uniform
    const float* bp = (jbase < CD) ? (bq + jbase) : (bkv + (jbase - CD));
    #pragma unroll
    for (int nf = 0; nf < 4; ++nf) {
        const float bv = bp[nf * 16 + colw];
        #pragma unroll
        for (int mf = 0; mf < 4; ++mf)
            #pragma unroll
            for (int r = 0; r < 4; ++r) acc[mf][nf][r] += bv;
    }
    const float qscale = (jbase < CD) ? 0.125f : 1.0f;
    unsigned short* dst; int jloc;
    if (jbase < CD)            { dst = Qb;  jloc = jbase; }
    else if (jbase < 2 * CD)   { dst = Kb;  jloc = jbase - CD; }
    else                       { dst = Vtb; jloc = jbase - 2 * CD; }
    const int h = jloc >> 6;

    if (jbase < 2 * CD) {
        // ---- Q/K: coalesced-in-d store ----
        #pragma unroll
        for (int mf = 0; mf < 4; ++mf) {
            #pragma unroll
            for (int r = 0; r < 4; ++r) {
                float t = 0.f;
                #pragma unroll
                for (int nf = 0; nf < 4; ++nf) t += acc[mf][nf][r] * acc[mf][nf][r];
                t += __shfl_xor(t, 1);
                t += __shfl_xor(t, 2);
                t += __shfl_xor(t, 4);
                t += __shfl_xor(t, 8);
                const float inv = qscale / fmaxf(sqrtf(t), 1e-12f);
                const int i  = i0 + mf * 16 + grp * 4 + r;
                const int bt = i >> 9, li = i & 511;
                #pragma unroll
                for (int nf = 0; nf < 4; ++nf) {
                    const int d = nf * 16 + colw;
                    dst[(((size_t)(bt * HEADS + h)) * LSEQ + li) * DH + d] =
                        f2bf(acc[mf][nf][r] * inv);
                }
            }
        }
    } else {
        // ---- V: per-wave LDS bounce transpose -> coalesced-in-l store ----
        unsigned short* buf = &Vb[w][0];
        const int bt = i0 >> 9, lt = (i0 & 511) >> 6;   // one 64-token tile
        unsigned short* vdst = dst + (((size_t)(bt * HEADS + h)) * 8 + lt) * 4096;
        #pragma unroll
        for (int mf = 0; mf < 4; ++mf) {
            float inv[4];
            #pragma unroll
            for (int r = 0; r < 4; ++r) {
                float t = 0.f;
                #pragma unroll
                for (int nf = 0; nf < 4; ++nf) t += acc[mf][nf][r] * acc[mf][nf][r];
                t += __shfl_xor(t, 1);
                t += __shfl_xor(t, 2);
                t += __shfl_xor(t, 4);
                t += __shfl_xor(t, 8);
                inv[r] = 1.0f / fmaxf(sqrtf(t), 1e-12f);
            }
            const int lo = mf * 16;                     // token offset in tile
            #pragma unroll
            for (int nf = 0; nf < 4; ++nf) {
                #pragma unroll
                for (int r = 0; r < 4; ++r)
                    buf[(grp * 4 + r) * 20 + colw] = f2bf(acc[mf][nf][r] * inv[r]);
                unsigned short tv[4];
                #pragma unroll
                for (int r2 = 0; r2 < 4; ++r2)
                    tv[r2] = buf[colw * 20 + grp * 4 + r2];
                #pragma unroll
                for (int r2 = 0; r2 < 4; ++r2) {
                    const int d = nf * 16 + grp * 4 + r2;
                    vdst[d * 64 + lo + colw] = tv[r2];   // lanes contiguous in l
                }
            }
        }
    }
}

// ========== 2-phase dbuf GEMM core, FP8 inputs, BK=128 (proj_out) ==========
static __device__ __forceinline__ void gemm128_fp8_core(
    const unsigned char* __restrict__ Ap,   // [M][1024] fp8 row-major
    const unsigned char* __restrict__ Bp,   // [N][1024] fp8 row-major
    int i0, int n0, char* lds, f32x4 acc[4][4])
{
    const int tid  = threadIdx.x;
    const int wv   = tid >> 6;        // 0..3
    const int lane = tid & 63;
    const int colw = lane & 15;
    const int grp  = lane >> 4;
    const int wr   = wv >> 1;
    const int wc   = wv & 1;

    const int srow0 = lane >> 3;
    const int sclog = (lane & 7) ^ (srow0 & 7);
    const int adst  = wv * 32 * 128;
    const int bdst  = 16384 + wv * 32 * 128;

    int aoff[4][4], boff[4][4];
    #pragma unroll
    for (int ks = 0; ks < 4; ++ks) {
        #pragma unroll
        for (int f = 0; f < 4; ++f) {
            const int ra = wr * 64 + f * 16 + colw;
            const int rb = wc * 64 + f * 16 + colw;
            const int ch = ks * 2 + (grp >> 1);
            aoff[ks][f] = ra * 128 + ((ch ^ (ra & 7)) << 4) + (grp & 1) * 8;
            boff[ks][f] = 16384 + rb * 128 + ((ch ^ (rb & 7)) << 4) + (grp & 1) * 8;
        }
    }

    const int NT = CD / 128;   // 8 K-tiles

    #pragma unroll
    for (int c = 0; c < 4; ++c) {
        const int row = wv * 32 + c * 8 + srow0;
        gload16(Ap + (size_t)(i0 + row) * CD + sclog * 16, lds + adst + c * 1024);
        gload16(Bp + (size_t)(n0 + row) * CD + sclog * 16, lds + bdst + c * 1024);
    }
    asm volatile("s_waitcnt vmcnt(0)" ::: "memory");
    __builtin_amdgcn_s_barrier();

    for (int t = 0; t < NT; ++t) {
        char* const cb = lds + (t & 1) * 32768;
        char* const nb = lds + ((t & 1) ^ 1) * 32768;

        if (t + 1 < NT) {
            const int kt = (t + 1) * 128;
            #pragma unroll
            for (int c = 0; c < 4; ++c) {
                const int row = wv * 32 + c * 8 + srow0;
                gload16(Ap + (size_t)(i0 + row) * CD + kt + sclog * 16, nb + adst + c * 1024);
                gload16(Bp + (size_t)(n0 + row) * CD + kt + sclog * 16, nb + bdst + c * 1024);
            }
        }
        long long af[4][4], bf[4][4];
        #pragma unroll
        for (int ks = 0; ks < 4; ++ks) {
            #pragma unroll
            for (int f = 0; f < 4; ++f) {
                af[ks][f] = *(const long long*)(cb + aoff[ks][f]);
                bf[ks][f] = *(const long long*)(cb + boff[ks][f]);
            }
        }
        __builtin_amdgcn_s_setprio(1);
        #pragma unroll
        for (int ks = 0; ks < 4; ++ks)
            #pragma unroll
            for (int mf = 0; mf < 4; ++mf)
                #pragma unroll
                for (int nf = 0; nf < 4; ++nf)
                    acc[mf][nf] = __builtin_amdgcn_mfma_f32_16x16x32_fp8_fp8(
                        af[ks][mf], bf[ks][nf], acc[mf][nf], 0, 0, 0);
        __builtin_amdgcn_s_setprio(0);

        asm volatile("s_waitcnt vmcnt(0)" ::: "memory");
        __builtin_amdgcn_s_barrier();
    }
}

// ---------------- Kernel 2: flash attention per (b,t,h) ----------
// Bounded-score softmax (|s|<=0.125): exp(s) directly, no max tracking.
// O written as fp8 e4m3 (feeds the fp8 out-projection directly).
__global__ __launch_bounds__(512)
void attn_kernel(const unsigned short* __restrict__ Qb,
                 const unsigned short* __restrict__ Kb,
                 const unsigned short* __restrict__ Vtb,   // tiled [bth][8][64][64]
                 unsigned char* __restrict__ Ob)
{
    __shared__ __attribute__((aligned(16))) unsigned short Ksm[64 * 64];
    __shared__ __attribute__((aligned(16))) unsigned short Vsm[64 * 64];
    __shared__ __attribute__((aligned(16))) unsigned short Psm[8][16 * 72];

    const int tid  = threadIdx.x;
    const int w    = tid >> 6;        // 0..7
    const int lane = tid & 63;
    const int colw = lane & 15;
    const int grp  = lane >> 4;

    const int bth = blockIdx.x & 255;     // head id (same XCD for all its q-tiles)
    const int qt  = blockIdx.x >> 8;      // 0..3
    const int q0  = qt * 128 + w * 16;    // wave's first q row

    const unsigned short* Qh = Qb  + (size_t)bth * LSEQ * DH;
    const unsigned short* Kh = Kb  + (size_t)bth * LSEQ * DH;
    const unsigned short* Vh = Vtb + (size_t)bth * LSEQ * DH;  // tiled

    short8 aq[2];
    #pragma unroll
    for (int ks = 0; ks < 2; ++ks)
        aq[ks] = *(const short8*)&Qh[(size_t)(q0 + colw) * DH + ks * 32 + grp * 8];

    const int srow   = w * 8 + (lane >> 3);          // 0..63
    const int schunk = (lane & 7) ^ (srow & 7);      // swizzled 16B chunk
    const int goff   = srow * DH + schunk * 8;       // element offset in 8KB tile
    char* const kdst = (char*)Ksm + w * 1024;
    char* const vdst = (char*)Vsm + w * 1024;

    float plsum[4] = {0.f, 0.f, 0.f, 0.f};
    f32x4 oacc[4] = {};

    for (int t = 0; t < 8; ++t) {
        gload16(Kh + t * 4096 + goff, kdst);
        gload16(Vh + t * 4096 + goff, vdst);
        __syncthreads();                 // drains vmcnt -> tiles ready

        f32x4 s[4] = {};
        #pragma unroll
        for (int ks = 0; ks < 2; ++ks) {
            #pragma unroll
            for (int nf = 0; nf < 4; ++nf) {
                const int rowb = nf * 16 + colw;
                const short8 bk = *(const short8*)((char*)Ksm + rowb * 128 +
                                       ((((ks * 4 + grp) ^ (rowb & 7))) << 4));
                s[nf] = __builtin_amdgcn_mfma_f32_16x16x32_bf16(aq[ks], bk, s[nf], 0, 0, 0);
            }
        }
        #pragma unroll
        for (int nf = 0; nf < 4; ++nf) {
            #pragma unroll
            for (int r = 0; r < 4; ++r) {
                const float p = __expf(s[nf][r]);
                plsum[r] += p;
                Psm[w][(grp * 4 + r) * 72 + nf * 16 + colw] = f2bf(p);
            }
        }
        #pragma unroll
        for (int ks2 = 0; ks2 < 2; ++ks2) {
            const short8 ap = *(const short8*)&Psm[w][colw * 72 + ks2 * 32 + grp * 8];
            #pragma unroll
            for (int nf = 0; nf < 4; ++nf) {
                const int rowv = nf * 16 + colw;
                const short8 bv = *(const short8*)((char*)Vsm + rowv * 128 +
                                       ((((ks2 * 4 + grp) ^ (rowv & 7))) << 4));
                oacc[nf] = __builtin_amdgcn_mfma_f32_16x16x32_bf16(ap, bv, oacc[nf], 0, 0, 0);
            }
        }
        __syncthreads();                 // protect LDS tiles before restage
    }

    float oinv[4];
    #pragma unroll
    for (int r = 0; r < 4; ++r) {
        float t = plsum[r];
        t += __shfl_xor(t, 1);
        t += __shfl_xor(t, 2);
        t += __shfl_xor(t, 4);
        t += __shfl_xor(t, 8);
        oinv[r] = 1.0f / t;
    }

    const int bt = bth >> 4, h = bth & 15;
    #pragma unroll
    for (int nf = 0; nf < 4; ++nf) {
        #pragma unroll
        for (int r = 0; r < 4; ++r) {
            const int i = bt * LSEQ + q0 + grp * 4 + r;
            const int c = h * 64 + nf * 16 + colw;
            Ob[(size_t)i * CD + c] = f2fp8(oacc[nf][r] * oinv[r]);
        }
    }
}

// ---------------- Kernel 3: output projection + bias + residual ----------
__global__ __launch_bounds__(256, 2)
void proj_out_kernel(const unsigned char* __restrict__ O8,
                     const unsigned char* __restrict__ wm8,
                     const float* __restrict__ bm,
                     const float* __restrict__ x, float* __restrict__ out)
{
    __shared__ __attribute__((aligned(16))) char lds[64 * 1024];

    // grid = 512. XCD partition: 16m x 4n rectangle per XCD.
    const int xcd = blockIdx.x & 7, wgl = blockIdx.x >> 3;   // wgl 0..63
    const int im  = (xcd & 3) * 16 + (wgl >> 2);
    const int in  = (xcd >> 2) * 4 + (wgl & 3);
    const int i0 = im * 128, j0 = in * 128;

    const int tid  = threadIdx.x;
    const int wv   = tid >> 6;
    const int lane = tid & 63;
    const int colw = lane & 15;
    const int grp  = lane >> 4;
    const int wr   = wv >> 1, wc = wv & 1;

    f32x4 acc[4][4] = {};
    gemm128_fp8_core(O8, wm8, i0, j0, lds, acc);

    #pragma unroll
    for (int nf = 0; nf < 4; ++nf) {
        const int j = j0 + wc * 64 + nf * 16 + colw;
        const float bv = bm[j];
        #pragma unroll
        for (int mf = 0; mf < 4; ++mf) {
            #pragma unroll
            for (int r = 0; r < 4; ++r) {
                const int i = i0 + wr * 64 + mf * 16 + grp * 4 + r;
                out[(size_t)i * CD + j] = acc[mf][nf][r] + bv + x[(size_t)i * CD + j];
            }
        }
    }
}

extern "C" void kernel_launch(void* const* d_in, const int* in_sizes, int n_in,
                              void* d_out, int out_size, void* d_ws, size_t ws_size,
                              hipStream_t stream) {
    const float* x   = (const float*)d_in[0];
    const float* wq  = (const float*)d_in[1];
    const float* bq  = (const float*)d_in[2];
    const float* wkv = (const float*)d_in[3];
    const float* bkv = (const float*)d_in[4];
    const float* wm  = (const float*)d_in[5];
    const float* bm  = (const float*)d_in[6];
    float* out = (float*)d_out;

    // ws layout (64 MB, timeline-aliased, byte offsets):
    //  [0,16M):  x8 fp8 (cvt->proj_qkv), then O8 fp8 (attn->proj_out)
    //  [16M,32M): Qb bf16 (proj_qkv->attn), then wm8 fp8 (cvt-after-attn->proj_out)
    //  [32M,48M): Kb bf16   [48M,64M): Vtb bf16
    // wqkvf (frag-major fp8, 3MB) lives in d_out (dead before proj_out writes it).
    char* base = (char*)d_ws;
    unsigned char*  x8    = (unsigned char*)base;
    unsigned char*  O8    = (unsigned char*)base;    // alias (x8 dead after proj_qkv)
    unsigned short* Qb    = (unsigned short*)(base + 16 * 1024 * 1024);
    unsigned char*  wm8   = (unsigned char*)(base + 16 * 1024 * 1024);  // alias after attn
    unsigned short* Kb    = (unsigned short*)(base + 32 * 1024 * 1024);
    unsigned short* Vtb   = (unsigned short*)(base + 48 * 1024 * 1024);
    unsigned char*  wqkvf = (unsigned char*)d_out;

    cvt_fp8_kernel<<<2048, 256, 0, stream>>>(x, x8, (MROWS * CD) / 8);
    // wq -> frag slots [0, 2048); wkv -> frag slots [2048, 6144)  (slot = 512B)
    cvt_frag8_kernel<<<512,  256, 0, stream>>>(wq,  wqkvf,               2048 * 64);
    cvt_frag8_kernel<<<1024, 256, 0, stream>>>(wkv, wqkvf + 2048 * 512,  4096 * 64);
    proj_qkv_kernel<<<768, 512, 0, stream>>>(x8, wqkvf, bq, bkv, Qb, Kb, Vtb);
    attn_kernel<<<1024, 512, 0, stream>>>(Qb, Kb, Vtb, O8);
    cvt_fp8_kernel<<<512, 256, 0, stream>>>(wm, wm8, (CD * CD) / 8);
    proj_out_kernel<<<512, 256, 0, stream>>>(O8, wm8, bm, x, out);
}